// Round 1
// baseline (103.961 us; speedup 1.0000x reference)
//
#include <hip/hip_runtime.h>
#include <math.h>

#define EPSF 1e-6f

constexpr int B = 8, N = 2048, M = 16, S = 100;
constexpr int MAIN_BLOCKS = B * (N / 64);         // 256: pcl_to_prim, 64 points each
constexpr int PRIM_BLOCKS = B * M * 2;            // 256: prim_to_pcl, (b,m) x half-of-S
constexpr int TOTAL_BLOCKS = MAIN_BLOCKS + PRIM_BLOCKS;  // 512
// NOTE: block i and i+256 land on the same CU under round-robin dispatch, so the
// main/prim split [0,256)/[256,512) already pairs one heavy main block with one
// lighter prim block per CU. Do not interleave even/odd (same parity -> same kind).

__device__ __forceinline__ float fexp_d(float x, float p) {
    float sg = (x > 0.f) ? 1.f : ((x < 0.f) ? -1.f : 0.f);
    return sg * __powf(fabsf(x) + EPSF, p);
}

// quaternion (w,x,y,z) at rot[bm*4..] -> row-major 3x3
__device__ __forceinline__ void quat_R(const float* __restrict__ rot, int bm, float R[9]) {
    float w = rot[bm * 4 + 0], x = rot[bm * 4 + 1], y = rot[bm * 4 + 2], z = rot[bm * 4 + 3];
    float inv = 1.0f / (sqrtf(w * w + x * x + y * y + z * z) + EPSF);
    w *= inv; x *= inv; y *= inv; z *= inv;
    R[0] = 1.f - 2.f * (y * y + z * z); R[1] = 2.f * (x * y - w * z); R[2] = 2.f * (x * z + w * y);
    R[3] = 2.f * (x * y + w * z); R[4] = 1.f - 2.f * (x * x + z * z); R[5] = 2.f * (y * z - w * x);
    R[6] = 2.f * (x * z - w * y); R[7] = 2.f * (y * z + w * x); R[8] = 1.f - 2.f * (x * x + y * y);
}

// surface point; w component carries |P|^2 for the expanded-distance trick
__device__ __forceinline__ float4 surf_point(
    const float* __restrict__ sizep, const float* __restrict__ seps,
    const float* __restrict__ deform, const float* __restrict__ etas,
    const float* __restrict__ omegas, int bm, int s)
{
    float e1 = seps[bm * 2 + 0], e2 = seps[bm * 2 + 1];
    float a1 = sizep[bm * 3 + 0], a2 = sizep[bm * 3 + 1], a3 = sizep[bm * 3 + 2];
    float d0 = deform[bm * 2 + 0], d1 = deform[bm * 2 + 1];
    float se_, ce_, sw_, cw_;
    __sincosf(etas[s], &se_, &ce_);
    __sincosf(omegas[s], &sw_, &cw_);
    float ce = fexp_d(ce_, e1);
    float se = fexp_d(se_, e1);
    float cw = fexp_d(cw_, e2);
    float sw = fexp_d(sw_, e2);
    float x = a1 * ce * cw;
    float y = a2 * ce * sw;
    float z = a3 * se;
    float fx = d0 * (z / a3) + 1.0f;
    float fy = d1 * (z / a3) + 1.0f;
    float4 P;
    P.x = fx * x; P.y = fy * y; P.z = z;
    P.w = P.x * P.x + P.y * P.y + P.z * P.z;
    return P;
}

// ---------------- single fused kernel ----------------
// blocks [0,256): pcl_to_prim; [256,512): prim_to_pcl.
__global__ __launch_bounds__(256) void k_all(
    const float* __restrict__ pcl, const float* __restrict__ trans,
    const float* __restrict__ rot, const float* __restrict__ sizep,
    const float* __restrict__ seps, const float* __restrict__ deform,
    const float* __restrict__ probs,
    const float* __restrict__ etas, const float* __restrict__ omegas,
    float* __restrict__ out)
{
    __shared__ float4 pts[S * M];   // 25.6 KB  (prim path reuses [0..49])
    __shared__ float sbuf[20];      // prim path: sarea[0..15], wsum[16..19]

    int t = threadIdx.x;

    if (blockIdx.x < MAIN_BLOCKS) {
        // ---------- pcl_to_prim ----------
        int b  = blockIdx.x >> 5;        // 32 n-chunks per batch
        int n0 = (blockIdx.x & 31) * 64;

        for (int i = t; i < S * M; i += 256) {
            int s = i >> 4, m = i & 15;
            pts[i] = surf_point(sizep, seps, deform, etas, omegas, b * M + m, s);
        }
        __syncthreads();   // the ONLY barrier on this path

        int m  = t & 15;
        int nl = t >> 4;                 // block-level row base; wave w owns rows {4w..4w+3}+16j
        int bm = b * M + m;
        float R[9];
        quat_R(rot, bm, R);
        float tx = trans[bm * 3 + 0], ty = trans[bm * 3 + 1], tz = trans[bm * 3 + 2];

        // rotated points; keep -2*pt and |pt|^2 for expanded distance
        float mx[4], my[4], mz[4], psq[4], dmin[4];
#pragma unroll
        for (int j = 0; j < 4; j++) {
            int n = n0 + nl + 16 * j;
            float px = pcl[(b * N + n) * 3 + 0];
            float py = pcl[(b * N + n) * 3 + 1];
            float pz = pcl[(b * N + n) * 3 + 2];
            float dx = px - tx, dy = py - ty, dz = pz - tz;
            float X = R[0] * dx + R[1] * dy + R[2] * dz;
            float Y = R[3] * dx + R[4] * dy + R[5] * dz;
            float Z = R[6] * dx + R[7] * dy + R[8] * dz;
            mx[j] = -2.f * X; my[j] = -2.f * Y; mz[j] = -2.f * Z;
            psq[j] = X * X + Y * Y + Z * Z;
            dmin[j] = 3.4e38f;
        }

        // min over s of (|P|^2 - 2 P.pt); |pt|^2 added afterwards
        for (int s = 0; s < S; s++) {
            float4 P = pts[s * M + m];
#pragma unroll
            for (int j = 0; j < 4; j++) {
                float d = fmaf(P.x, mx[j], P.w);
                d = fmaf(P.y, my[j], d);
                d = fmaf(P.z, mz[j], d);
                dmin[j] = fminf(dmin[j], d);
            }
        }

        // ---- in-wave cumprod-sorted sum (no LDS, no barrier, all 4 waves) ----
        // Each 16-lane group holds the full m=0..15 key vector for one n-row per j.
        // term_i = key_i * p_i * prod_{(key_k,k) <stable< (key_i,i)} (1 - p_k)
        float pv  = probs[bm];           // per-lane (m varies across lanes)
        float acc = 0.f;
#pragma unroll
        for (int j = 0; j < 4; j++) {
            float key = dmin[j] + psq[j];
            float prod = 1.f;
#pragma unroll
            for (int k = 0; k < 16; k++) {
                float bk = __shfl(key, k, 16);          // broadcast within 16-lane group
                bool before = (bk < key) || (bk == key && k < m);  // stable tie-break
                float omp = 1.f - probs[b * M + k];     // wave-uniform -> s_load
                prod *= before ? omp : 1.f;
            }
            acc += key * pv * prod;
        }
        // all 64 rows' terms sum into the same scalar: full-wave reduce
        for (int off = 32; off >= 1; off >>= 1) acc += __shfl_down(acc, off);
        if ((t & 63) == 0) atomicAdd(out, acc * (1.0f / (B * N)));
    } else {
        // ---------- prim_to_pcl ----------
        int pb = blockIdx.x - MAIN_BLOCKS;
        int bm = pb >> 1, q = pb & 1;
        int b = bm >> 4, m = bm & 15;
        int s0 = q * 50;

        float4* spts = pts;          // [0..49]
        float* sarea = sbuf;         // [0..15]
        float* wsum  = sbuf + 16;    // [16..19]

        if (t < 50) spts[t] = surf_point(sizep, seps, deform, etas, omegas, bm, s0 + t);
        if (t >= 64 && t < 64 + M) {
            int mm = t - 64;
            float s0s = sizep[(b * M + mm) * 3 + 0];
            float s1s = sizep[(b * M + mm) * 3 + 1];
            float s2s = sizep[(b * M + mm) * 3 + 2];
            float tt = __powf(s0s * s1s, 1.6f) / 3.f + __powf(s0s * s2s, 1.6f) / 3.f
                     + __powf(s1s * s2s, 1.6f) / 3.f;
            sarea[mm] = 4.0f * 3.14159265358979323846f * __powf(tt, 0.625f);
        }
        __syncthreads();

        float R[9];
        quat_R(rot, bm, R);
        float tx = trans[bm * 3 + 0], ty = trans[bm * 3 + 1], tz = trans[bm * 3 + 2];

        int w = t >> 6, lane = t & 63;
        int cnt = (w < 2) ? 13 : 12;
        int off = (w < 2) ? w * 13 : 26 + (w - 2) * 12;

        float px[13], py[13], pz[13], mins[13];
#pragma unroll
        for (int k = 0; k < 13; k++) {
            int sl = (k < cnt) ? (off + k) : off;   // pad entries excluded from sum later
            float4 P = spts[sl];
            px[k] = P.x; py[k] = P.y; pz[k] = P.z;
            mins[k] = 3.4e38f;
        }

        // min over n of (|X|^2 - 2 P_k.X); |P_k|^2 added after reduction
        for (int i = 0; i < 32; i++) {
            int n = i * 64 + lane;
            const float* pp = pcl + (b * N + n) * 3;
            float dx = pp[0] - tx, dy = pp[1] - ty, dz = pp[2] - tz;
            float X = R[0] * dx + R[1] * dy + R[2] * dz;
            float Y = R[3] * dx + R[4] * dy + R[5] * dz;
            float Z = R[6] * dx + R[7] * dy + R[8] * dz;
            float mX = -2.f * X, mY = -2.f * Y, mZ = -2.f * Z;
            float Xsq = X * X + Y * Y + Z * Z;
#pragma unroll
            for (int k = 0; k < 13; k++) {
                float d = fmaf(px[k], mX, Xsq);
                d = fmaf(py[k], mY, d);
                d = fmaf(pz[k], mZ, d);
                mins[k] = fminf(mins[k], d);
            }
        }

        float sum = 0.f;
#pragma unroll
        for (int k = 0; k < 13; k++) {
            float v = mins[k];
            for (int o = 32; o >= 1; o >>= 1) v = fminf(v, __shfl_down(v, o));
            int sl = (k < cnt) ? (off + k) : off;
            v += spts[sl].w;                       // add back |P_k|^2
            sum += (k < cnt) ? v : 0.f;
        }

        if (lane == 0) wsum[w] = sum;
        __syncthreads();
        if (t == 0) {
            float total = wsum[0] + wsum[1] + wsum[2] + wsum[3];
            float asum = 0.f;
            for (int mm = 0; mm < M; mm++) asum += sarea[mm];
            float area = (float)M * sarea[m] / asum;
            atomicAdd(out, total * area * (1.0f / (S * B * M)));
        }
    }
}

extern "C" void kernel_launch(void* const* d_in, const int* in_sizes, int n_in,
                              void* d_out, int out_size, void* d_ws, size_t ws_size,
                              hipStream_t stream)
{
    const float* pcl    = (const float*)d_in[0];
    const float* trans  = (const float*)d_in[1];
    const float* rot    = (const float*)d_in[2];
    const float* sizep  = (const float*)d_in[3];
    const float* seps   = (const float*)d_in[4];
    const float* deform = (const float*)d_in[5];
    const float* probs  = (const float*)d_in[6];
    const float* etas   = (const float*)d_in[7];
    const float* omegas = (const float*)d_in[8];
    float* out = (float*)d_out;

    k_all<<<TOTAL_BLOCKS, 256, 0, stream>>>(pcl, trans, rot, sizep, seps, deform,
                                            probs, etas, omegas, out);
}

// Round 2
// 93.104 us; speedup vs baseline: 1.1166x; 1.1166x over previous
//
#include <hip/hip_runtime.h>
#include <math.h>

#define EPSF 1e-6f

constexpr int B = 8, N = 2048, M = 16, S = 100;
constexpr int MAIN_BLOCKS = B * (N / 64);         // 256: pcl_to_prim, 64 points each
constexpr int PRIM_BLOCKS = B * M * 2;            // 256: prim_to_pcl, (b,m) x half-of-S
constexpr int TOTAL_BLOCKS = MAIN_BLOCKS + PRIM_BLOCKS;  // 512
constexpr int NPART = MAIN_BLOCKS * 4 + PRIM_BLOCKS;     // 1280 partials in d_ws

__device__ __forceinline__ float fexp_d(float x, float p) {
    float sg = (x > 0.f) ? 1.f : ((x < 0.f) ? -1.f : 0.f);
    return sg * __powf(fabsf(x) + EPSF, p);
}

// quaternion (w,x,y,z) at rot[bm*4..] -> row-major 3x3
__device__ __forceinline__ void quat_R(const float* __restrict__ rot, int bm, float R[9]) {
    float w = rot[bm * 4 + 0], x = rot[bm * 4 + 1], y = rot[bm * 4 + 2], z = rot[bm * 4 + 3];
    float inv = 1.0f / (sqrtf(w * w + x * x + y * y + z * z) + EPSF);
    w *= inv; x *= inv; y *= inv; z *= inv;
    R[0] = 1.f - 2.f * (y * y + z * z); R[1] = 2.f * (x * y - w * z); R[2] = 2.f * (x * z + w * y);
    R[3] = 2.f * (x * y + w * z); R[4] = 1.f - 2.f * (x * x + z * z); R[5] = 2.f * (y * z - w * x);
    R[6] = 2.f * (x * z - w * y); R[7] = 2.f * (y * z + w * x); R[8] = 1.f - 2.f * (x * x + y * y);
}

// surface point; w component carries |P|^2 for the expanded-distance trick
__device__ __forceinline__ float4 surf_point(
    const float* __restrict__ sizep, const float* __restrict__ seps,
    const float* __restrict__ deform, const float* __restrict__ etas,
    const float* __restrict__ omegas, int bm, int s)
{
    float e1 = seps[bm * 2 + 0], e2 = seps[bm * 2 + 1];
    float a1 = sizep[bm * 3 + 0], a2 = sizep[bm * 3 + 1], a3 = sizep[bm * 3 + 2];
    float d0 = deform[bm * 2 + 0], d1 = deform[bm * 2 + 1];
    float se_, ce_, sw_, cw_;
    __sincosf(etas[s], &se_, &ce_);
    __sincosf(omegas[s], &sw_, &cw_);
    float ce = fexp_d(ce_, e1);
    float se = fexp_d(se_, e1);
    float cw = fexp_d(cw_, e2);
    float sw = fexp_d(sw_, e2);
    float x = a1 * ce * cw;
    float y = a2 * ce * sw;
    float z = a3 * se;
    float fx = d0 * (z / a3) + 1.0f;
    float fy = d1 * (z / a3) + 1.0f;
    float4 P;
    P.x = fx * x; P.y = fy * y; P.z = z;
    P.w = P.x * P.x + P.y * P.y + P.z * P.z;
    return P;
}

// ---------------- fused main kernel ----------------
// blocks [0,256): pcl_to_prim; [256,512): prim_to_pcl.
// NO atomics: every wave/block writes a disjoint partial into part[] (d_ws);
// k_reduce sums them. (Round-1 lesson: same-address atomicAdd costs ~14 ns
// each, fully serialized in the end-of-kernel burst -> 18 us tail at 1280.)
__global__ __launch_bounds__(256) void k_all(
    const float* __restrict__ pcl, const float* __restrict__ trans,
    const float* __restrict__ rot, const float* __restrict__ sizep,
    const float* __restrict__ seps, const float* __restrict__ deform,
    const float* __restrict__ probs,
    const float* __restrict__ etas, const float* __restrict__ omegas,
    float* __restrict__ part)
{
    __shared__ float4 pts[S * M];   // 25.6 KB  (prim path reuses [0..49])
    __shared__ float sbuf[20];      // prim path: sarea[0..15], wsum[16..19]

    int t = threadIdx.x;

    if (blockIdx.x < MAIN_BLOCKS) {
        // ---------- pcl_to_prim ----------
        int b  = blockIdx.x >> 5;        // 32 n-chunks per batch
        int n0 = (blockIdx.x & 31) * 64;

        for (int i = t; i < S * M; i += 256) {
            int s = i >> 4, m = i & 15;
            pts[i] = surf_point(sizep, seps, deform, etas, omegas, b * M + m, s);
        }
        __syncthreads();   // the ONLY barrier on this path

        int m  = t & 15;
        int nl = t >> 4;
        int bm = b * M + m;
        float R[9];
        quat_R(rot, bm, R);
        float tx = trans[bm * 3 + 0], ty = trans[bm * 3 + 1], tz = trans[bm * 3 + 2];

        // rotated points; keep -2*pt and |pt|^2 for expanded distance
        float mx[4], my[4], mz[4], psq[4], dmin[4];
#pragma unroll
        for (int j = 0; j < 4; j++) {
            int n = n0 + nl + 16 * j;
            float px = pcl[(b * N + n) * 3 + 0];
            float py = pcl[(b * N + n) * 3 + 1];
            float pz = pcl[(b * N + n) * 3 + 2];
            float dx = px - tx, dy = py - ty, dz = pz - tz;
            float X = R[0] * dx + R[1] * dy + R[2] * dz;
            float Y = R[3] * dx + R[4] * dy + R[5] * dz;
            float Z = R[6] * dx + R[7] * dy + R[8] * dz;
            mx[j] = -2.f * X; my[j] = -2.f * Y; mz[j] = -2.f * Z;
            psq[j] = X * X + Y * Y + Z * Z;
            dmin[j] = 3.4e38f;
        }

        // min over s of (|P|^2 - 2 P.pt); double-buffered 4-deep LDS pipeline
        // (ds_read_b128 latency ~120 cyc; issue next group before computing current)
        float4 Pa[4], Pb[4];
#pragma unroll
        for (int u = 0; u < 4; u++) Pa[u] = pts[u * M + m];
        for (int s = 0; s < S; s += 4) {
#pragma unroll
            for (int u = 0; u < 4; u++) {
                int sn = s + 4 + u; if (sn >= S) sn = S - 1;
                Pb[u] = pts[sn * M + m];
            }
#pragma unroll
            for (int u = 0; u < 4; u++) {
                float4 P = Pa[u];
#pragma unroll
                for (int j = 0; j < 4; j++) {
                    float d = fmaf(P.x, mx[j], P.w);
                    d = fmaf(P.y, my[j], d);
                    d = fmaf(P.z, mz[j], d);
                    dmin[j] = fminf(dmin[j], d);
                }
            }
#pragma unroll
            for (int u = 0; u < 4; u++) Pa[u] = Pb[u];
        }

        // ---- in-wave cumprod-sorted sum (no LDS, no barrier, all 4 waves) ----
        float ompr[16];                  // wave-uniform -> SGPRs
#pragma unroll
        for (int k = 0; k < 16; k++) ompr[k] = 1.f - probs[b * M + k];
        float pv  = probs[bm];
        float acc = 0.f;
#pragma unroll
        for (int j = 0; j < 4; j++) {
            float key = dmin[j] + psq[j];
            float prod = 1.f;
#pragma unroll
            for (int k = 0; k < 16; k++) {
                float bk = __shfl(key, k, 16);          // broadcast within 16-lane group
                bool before = (bk < key) || (bk == key && k < m);  // stable tie-break
                prod *= before ? ompr[k] : 1.f;
            }
            acc += key * pv * prod;
        }
        // full-wave reduce; each wave writes its own disjoint partial
        for (int off = 32; off >= 1; off >>= 1) acc += __shfl_down(acc, off);
        if ((t & 63) == 0)
            part[blockIdx.x * 4 + (t >> 6)] = acc * (1.0f / (B * N));
    } else {
        // ---------- prim_to_pcl ----------
        int pb = blockIdx.x - MAIN_BLOCKS;
        int bm = pb >> 1, q = pb & 1;
        int b = bm >> 4, m = bm & 15;
        int s0 = q * 50;

        float4* spts = pts;          // [0..49]
        float* sarea = sbuf;         // [0..15]
        float* wsum  = sbuf + 16;    // [16..19]

        if (t < 50) spts[t] = surf_point(sizep, seps, deform, etas, omegas, bm, s0 + t);
        if (t >= 64 && t < 64 + M) {
            int mm = t - 64;
            float s0s = sizep[(b * M + mm) * 3 + 0];
            float s1s = sizep[(b * M + mm) * 3 + 1];
            float s2s = sizep[(b * M + mm) * 3 + 2];
            float tt = __powf(s0s * s1s, 1.6f) / 3.f + __powf(s0s * s2s, 1.6f) / 3.f
                     + __powf(s1s * s2s, 1.6f) / 3.f;
            sarea[mm] = 4.0f * 3.14159265358979323846f * __powf(tt, 0.625f);
        }
        __syncthreads();

        float R[9];
        quat_R(rot, bm, R);
        float tx = trans[bm * 3 + 0], ty = trans[bm * 3 + 1], tz = trans[bm * 3 + 2];

        int w = t >> 6, lane = t & 63;
        int cnt = (w < 2) ? 13 : 12;
        int off = (w < 2) ? w * 13 : 26 + (w - 2) * 12;

        float px[13], py[13], pz[13], mins[13];
#pragma unroll
        for (int k = 0; k < 13; k++) {
            int sl = (k < cnt) ? (off + k) : off;   // pad entries excluded from sum later
            float4 P = spts[sl];
            px[k] = P.x; py[k] = P.y; pz[k] = P.z;
            mins[k] = 3.4e38f;
        }

        // min over n of (|X|^2 - 2 P_k.X); 1-deep global prefetch hides L2 latency
        const float* pcb = pcl + b * N * 3;
        float cx = pcb[lane * 3 + 0], cy = pcb[lane * 3 + 1], cz = pcb[lane * 3 + 2];
        for (int i = 0; i < 32; i++) {
            int n2 = (i < 31) ? ((i + 1) * 64 + lane) : lane;
            float nx = pcb[n2 * 3 + 0], ny = pcb[n2 * 3 + 1], nz = pcb[n2 * 3 + 2];
            float dx = cx - tx, dy = cy - ty, dz = cz - tz;
            float X = R[0] * dx + R[1] * dy + R[2] * dz;
            float Y = R[3] * dx + R[4] * dy + R[5] * dz;
            float Z = R[6] * dx + R[7] * dy + R[8] * dz;
            float mX = -2.f * X, mY = -2.f * Y, mZ = -2.f * Z;
            float Xsq = X * X + Y * Y + Z * Z;
#pragma unroll
            for (int k = 0; k < 13; k++) {
                float d = fmaf(px[k], mX, Xsq);
                d = fmaf(py[k], mY, d);
                d = fmaf(pz[k], mZ, d);
                mins[k] = fminf(mins[k], d);
            }
            cx = nx; cy = ny; cz = nz;
        }

        float sum = 0.f;
#pragma unroll
        for (int k = 0; k < 13; k++) {
            float v = mins[k];
            for (int o = 32; o >= 1; o >>= 1) v = fminf(v, __shfl_down(v, o));
            int sl = (k < cnt) ? (off + k) : off;
            v += spts[sl].w;                       // add back |P_k|^2
            sum += (k < cnt) ? v : 0.f;
        }

        if (lane == 0) wsum[w] = sum;
        __syncthreads();
        if (t == 0) {
            float total = wsum[0] + wsum[1] + wsum[2] + wsum[3];
            float asum = 0.f;
            for (int mm = 0; mm < M; mm++) asum += sarea[mm];
            float area = (float)M * sarea[m] / asum;
            part[MAIN_BLOCKS * 4 + pb] = total * area * (1.0f / (S * B * M));
        }
    }
}

// ---------------- tiny deterministic reduce ----------------
__global__ __launch_bounds__(256) void k_reduce(const float* __restrict__ part,
                                               float* __restrict__ out)
{
    __shared__ float ws[4];
    int t = threadIdx.x;
    float s = 0.f;
    for (int i = t; i < NPART; i += 256) s += part[i];
    for (int off = 32; off >= 1; off >>= 1) s += __shfl_down(s, off);
    if ((t & 63) == 0) ws[t >> 6] = s;
    __syncthreads();
    if (t == 0) out[0] = ws[0] + ws[1] + ws[2] + ws[3];
}

extern "C" void kernel_launch(void* const* d_in, const int* in_sizes, int n_in,
                              void* d_out, int out_size, void* d_ws, size_t ws_size,
                              hipStream_t stream)
{
    const float* pcl    = (const float*)d_in[0];
    const float* trans  = (const float*)d_in[1];
    const float* rot    = (const float*)d_in[2];
    const float* sizep  = (const float*)d_in[3];
    const float* seps   = (const float*)d_in[4];
    const float* deform = (const float*)d_in[5];
    const float* probs  = (const float*)d_in[6];
    const float* etas   = (const float*)d_in[7];
    const float* omegas = (const float*)d_in[8];
    float* out  = (float*)d_out;
    float* partials = (float*)d_ws;

    k_all<<<TOTAL_BLOCKS, 256, 0, stream>>>(pcl, trans, rot, sizep, seps, deform,
                                            probs, etas, omegas, partials);
    k_reduce<<<1, 256, 0, stream>>>(partials, out);
}

// Round 4
// 91.737 us; speedup vs baseline: 1.1332x; 1.0149x over previous
//
#include <hip/hip_runtime.h>
#include <math.h>

#define EPSF 1e-6f

constexpr int B = 8, N = 2048, M = 16, S = 100;
constexpr int MAIN_BLOCKS = B * (N / 64);         // 256: pcl_to_prim, 64 points each
constexpr int PRIM_BLOCKS = B * M * 2;            // 256: prim_to_pcl, (b,m) x half-of-S
constexpr int TOTAL_BLOCKS = MAIN_BLOCKS + PRIM_BLOCKS;  // 512 worker blocks
constexpr int NPART = MAIN_BLOCKS * 4 + PRIM_BLOCKS;     // 1280 partials in d_ws

// fast hw transcendentals (avoid __exp2f/__log2f: glibc math.h macro collision)
__device__ __forceinline__ float hw_exp2(float x) { return __builtin_amdgcn_exp2f(x); }
__device__ __forceinline__ float hw_log2(float x) { return __builtin_amdgcn_logf(x); }

__device__ __forceinline__ float fexp_d(float x, float p) {
    float sg = (x > 0.f) ? 1.f : ((x < 0.f) ? -1.f : 0.f);
    return sg * __powf(fabsf(x) + EPSF, p);
}

__device__ __forceinline__ float sgn_d(float x) {
    return (x > 0.f) ? 1.f : ((x < 0.f) ? -1.f : 0.f);
}

// quaternion (w,x,y,z) at rot[bm*4..] -> row-major 3x3
__device__ __forceinline__ void quat_R(const float* __restrict__ rot, int bm, float R[9]) {
    float w = rot[bm * 4 + 0], x = rot[bm * 4 + 1], y = rot[bm * 4 + 2], z = rot[bm * 4 + 3];
    float inv = 1.0f / (sqrtf(w * w + x * x + y * y + z * z) + EPSF);
    w *= inv; x *= inv; y *= inv; z *= inv;
    R[0] = 1.f - 2.f * (y * y + z * z); R[1] = 2.f * (x * y - w * z); R[2] = 2.f * (x * z + w * y);
    R[3] = 2.f * (x * y + w * z); R[4] = 1.f - 2.f * (x * x + z * z); R[5] = 2.f * (y * z - w * x);
    R[6] = 2.f * (x * z - w * y); R[7] = 2.f * (y * z + w * x); R[8] = 1.f - 2.f * (x * x + y * y);
}

// surface point (prim path; 50 pts/block, transcendental cost irrelevant there)
__device__ __forceinline__ float4 surf_point(
    const float* __restrict__ sizep, const float* __restrict__ seps,
    const float* __restrict__ deform, const float* __restrict__ etas,
    const float* __restrict__ omegas, int bm, int s)
{
    float e1 = seps[bm * 2 + 0], e2 = seps[bm * 2 + 1];
    float a1 = sizep[bm * 3 + 0], a2 = sizep[bm * 3 + 1], a3 = sizep[bm * 3 + 2];
    float d0 = deform[bm * 2 + 0], d1 = deform[bm * 2 + 1];
    float se_, ce_, sw_, cw_;
    __sincosf(etas[s], &se_, &ce_);
    __sincosf(omegas[s], &sw_, &cw_);
    float ce = fexp_d(ce_, e1);
    float se = fexp_d(se_, e1);
    float cw = fexp_d(cw_, e2);
    float sw = fexp_d(sw_, e2);
    float x = a1 * ce * cw;
    float y = a2 * ce * sw;
    float z = a3 * se;
    float fx = d0 * (z / a3) + 1.0f;
    float fy = d1 * (z / a3) + 1.0f;
    float4 P;
    P.x = fx * x; P.y = fy * y; P.z = z;
    P.w = P.x * P.x + P.y * P.y + P.z * P.z;
    return P;
}

// ---------------- single fused kernel, 513 blocks ----------------
// [0,256): pcl_to_prim; [256,512): prim_to_pcl; block 512: flag-gated reducer.
// No same-address atomics anywhere (round-1 lesson: ~14 ns each, serialized).
// Flags are agent-scope release/acquire and self-resetting, so correctness
// depends neither on dispatch order (workers never wait) nor on ws poisoning.
__global__ __launch_bounds__(256) void k_all(
    const float* __restrict__ pcl, const float* __restrict__ trans,
    const float* __restrict__ rot, const float* __restrict__ sizep,
    const float* __restrict__ seps, const float* __restrict__ deform,
    const float* __restrict__ probs,
    const float* __restrict__ etas, const float* __restrict__ omegas,
    float* __restrict__ part, unsigned int* __restrict__ flags,
    float* __restrict__ out)
{
    __shared__ float4 pts[S * M];   // 25.6 KB  (prim path reuses [0..49])
    __shared__ float trig[S * 8];   // 3.2 KB: per-s {log2|c|,sgn} x {ce,se,cw,sw}
    __shared__ float sbuf[20];      // prim path: sarea[0..15], wsum[16..19]

    int t = threadIdx.x;

    if (blockIdx.x < MAIN_BLOCKS) {
        // ---------- pcl_to_prim ----------
        int b  = blockIdx.x >> 5;        // 32 n-chunks per batch
        int n0 = (blockIdx.x & 31) * 64;

        // stage 1: per-s trig+log table (sincos/log depend only on s, not m)
        if (t < S) {
            float se_, ce_, sw_, cw_;
            __sincosf(etas[t], &se_, &ce_);
            __sincosf(omegas[t], &sw_, &cw_);
            trig[t * 8 + 0] = hw_log2(fabsf(ce_) + EPSF);
            trig[t * 8 + 1] = sgn_d(ce_);
            trig[t * 8 + 2] = hw_log2(fabsf(se_) + EPSF);
            trig[t * 8 + 3] = sgn_d(se_);
            trig[t * 8 + 4] = hw_log2(fabsf(cw_) + EPSF);
            trig[t * 8 + 5] = sgn_d(cw_);
            trig[t * 8 + 6] = hw_log2(fabsf(sw_) + EPSF);
            trig[t * 8 + 7] = sgn_d(sw_);
        }
        __syncthreads();

        // stage 2: 1600 surface points, 4 exp2 each (was 12 transcendentals)
        for (int i = t; i < S * M; i += 256) {
            int s = i >> 4, mm = i & 15;
            int bmi = b * M + mm;
            float e1 = seps[bmi * 2 + 0], e2 = seps[bmi * 2 + 1];
            float a1 = sizep[bmi * 3 + 0], a2 = sizep[bmi * 3 + 1], a3 = sizep[bmi * 3 + 2];
            float d0 = deform[bmi * 2 + 0], d1 = deform[bmi * 2 + 1];
            float ce = trig[s * 8 + 1] * hw_exp2(e1 * trig[s * 8 + 0]);
            float se = trig[s * 8 + 3] * hw_exp2(e1 * trig[s * 8 + 2]);
            float cw = trig[s * 8 + 5] * hw_exp2(e2 * trig[s * 8 + 4]);
            float sw = trig[s * 8 + 7] * hw_exp2(e2 * trig[s * 8 + 6]);
            float x = a1 * ce * cw;
            float y = a2 * ce * sw;
            float z = a3 * se;
            float fx = fmaf(d0, se, 1.0f);   // z/a3 == se
            float fy = fmaf(d1, se, 1.0f);
            float4 P;
            P.x = fx * x; P.y = fy * y; P.z = z;
            P.w = P.x * P.x + P.y * P.y + P.z * P.z;
            pts[i] = P;
        }
        __syncthreads();

        int m  = t & 15;
        int nl = t >> 4;
        int bm = b * M + m;
        float R[9];
        quat_R(rot, bm, R);
        float tx = trans[bm * 3 + 0], ty = trans[bm * 3 + 1], tz = trans[bm * 3 + 2];

        // rotated points; keep -2*pt and |pt|^2 for expanded distance
        float mx[4], my[4], mz[4], psq[4], dmin[4];
#pragma unroll
        for (int j = 0; j < 4; j++) {
            int n = n0 + nl + 16 * j;
            float px = pcl[(b * N + n) * 3 + 0];
            float py = pcl[(b * N + n) * 3 + 1];
            float pz = pcl[(b * N + n) * 3 + 2];
            float dx = px - tx, dy = py - ty, dz = pz - tz;
            float X = R[0] * dx + R[1] * dy + R[2] * dz;
            float Y = R[3] * dx + R[4] * dy + R[5] * dz;
            float Z = R[6] * dx + R[7] * dy + R[8] * dz;
            mx[j] = -2.f * X; my[j] = -2.f * Y; mz[j] = -2.f * Z;
            psq[j] = X * X + Y * Y + Z * Z;
            dmin[j] = 3.4e38f;
        }

        // min over s of (|P|^2 - 2 P.pt); double-buffered 4-deep LDS pipeline
        float4 Pa[4], Pb[4];
#pragma unroll
        for (int u = 0; u < 4; u++) Pa[u] = pts[u * M + m];
        for (int s = 0; s < S; s += 4) {
#pragma unroll
            for (int u = 0; u < 4; u++) {
                int sn = s + 4 + u; if (sn >= S) sn = S - 1;
                Pb[u] = pts[sn * M + m];
            }
#pragma unroll
            for (int u = 0; u < 4; u++) {
                float4 P = Pa[u];
#pragma unroll
                for (int j = 0; j < 4; j++) {
                    float d = fmaf(P.x, mx[j], P.w);
                    d = fmaf(P.y, my[j], d);
                    d = fmaf(P.z, mz[j], d);
                    dmin[j] = fminf(dmin[j], d);
                }
            }
#pragma unroll
            for (int u = 0; u < 4; u++) Pa[u] = Pb[u];
        }

        // ---- in-wave cumprod-sorted sum ----
        float ompr[16];
#pragma unroll
        for (int k = 0; k < 16; k++) ompr[k] = 1.f - probs[b * M + k];
        float pv  = probs[bm];
        float acc = 0.f;
#pragma unroll
        for (int j = 0; j < 4; j++) {
            float key = dmin[j] + psq[j];
            float prod = 1.f;
#pragma unroll
            for (int k = 0; k < 16; k++) {
                float bk = __shfl(key, k, 16);
                bool before = (bk < key) || (bk == key && k < m);
                prod *= before ? ompr[k] : 1.f;
            }
            acc += key * pv * prod;
        }
        for (int off = 32; off >= 1; off >>= 1) acc += __shfl_down(acc, off);
        if ((t & 63) == 0)
            __hip_atomic_store(&part[blockIdx.x * 4 + (t >> 6)],
                               acc * (1.0f / (B * N)),
                               __ATOMIC_RELAXED, __HIP_MEMORY_SCOPE_AGENT);
        __syncthreads();   // all four partial stores issued before flag
        if (t == 0)
            __hip_atomic_store(&flags[blockIdx.x], 1u,
                               __ATOMIC_RELEASE, __HIP_MEMORY_SCOPE_AGENT);
    } else if (blockIdx.x < TOTAL_BLOCKS) {
        // ---------- prim_to_pcl ----------
        int pb = blockIdx.x - MAIN_BLOCKS;
        int bm = pb >> 1, q = pb & 1;
        int b = bm >> 4, m = bm & 15;
        int s0 = q * 50;

        float4* spts = pts;          // [0..49]
        float* sarea = sbuf;         // [0..15]
        float* wsum  = sbuf + 16;    // [16..19]

        if (t < 50) spts[t] = surf_point(sizep, seps, deform, etas, omegas, bm, s0 + t);
        if (t >= 64 && t < 64 + M) {
            int mm = t - 64;
            float s0s = sizep[(b * M + mm) * 3 + 0];
            float s1s = sizep[(b * M + mm) * 3 + 1];
            float s2s = sizep[(b * M + mm) * 3 + 2];
            float tt = __powf(s0s * s1s, 1.6f) / 3.f + __powf(s0s * s2s, 1.6f) / 3.f
                     + __powf(s1s * s2s, 1.6f) / 3.f;
            sarea[mm] = 4.0f * 3.14159265358979323846f * __powf(tt, 0.625f);
        }
        __syncthreads();

        float R[9];
        quat_R(rot, bm, R);
        float tx = trans[bm * 3 + 0], ty = trans[bm * 3 + 1], tz = trans[bm * 3 + 2];

        int w = t >> 6, lane = t & 63;
        int cnt = (w < 2) ? 13 : 12;
        int off = (w < 2) ? w * 13 : 26 + (w - 2) * 12;

        float px[13], py[13], pz[13], mins[13];
#pragma unroll
        for (int k = 0; k < 13; k++) {
            int sl = (k < cnt) ? (off + k) : off;
            float4 P = spts[sl];
            px[k] = P.x; py[k] = P.y; pz[k] = P.z;
            mins[k] = 3.4e38f;
        }

        // min over n; 1-deep global prefetch hides L2 latency
        const float* pcb = pcl + b * N * 3;
        float cx = pcb[lane * 3 + 0], cy = pcb[lane * 3 + 1], cz = pcb[lane * 3 + 2];
        for (int i = 0; i < 32; i++) {
            int n2 = (i < 31) ? ((i + 1) * 64 + lane) : lane;
            float nx = pcb[n2 * 3 + 0], ny = pcb[n2 * 3 + 1], nz = pcb[n2 * 3 + 2];
            float dx = cx - tx, dy = cy - ty, dz = cz - tz;
            float X = R[0] * dx + R[1] * dy + R[2] * dz;
            float Y = R[3] * dx + R[4] * dy + R[5] * dz;
            float Z = R[6] * dx + R[7] * dy + R[8] * dz;
            float mX = -2.f * X, mY = -2.f * Y, mZ = -2.f * Z;
            float Xsq = X * X + Y * Y + Z * Z;
#pragma unroll
            for (int k = 0; k < 13; k++) {
                float d = fmaf(px[k], mX, Xsq);
                d = fmaf(py[k], mY, d);
                d = fmaf(pz[k], mZ, d);
                mins[k] = fminf(mins[k], d);
            }
            cx = nx; cy = ny; cz = nz;
        }

        float sum = 0.f;
#pragma unroll
        for (int k = 0; k < 13; k++) {
            float v = mins[k];
            for (int o = 32; o >= 1; o >>= 1) v = fminf(v, __shfl_down(v, o));
            int sl = (k < cnt) ? (off + k) : off;
            v += spts[sl].w;
            sum += (k < cnt) ? v : 0.f;
        }

        if (lane == 0) wsum[w] = sum;
        __syncthreads();
        if (t == 0) {
            float total = wsum[0] + wsum[1] + wsum[2] + wsum[3];
            float asum = 0.f;
            for (int mm = 0; mm < M; mm++) asum += sarea[mm];
            float area = (float)M * sarea[m] / asum;
            __hip_atomic_store(&part[MAIN_BLOCKS * 4 + pb],
                               total * area * (1.0f / (S * B * M)),
                               __ATOMIC_RELAXED, __HIP_MEMORY_SCOPE_AGENT);
            __hip_atomic_store(&flags[blockIdx.x], 1u,
                               __ATOMIC_RELEASE, __HIP_MEMORY_SCOPE_AGENT);
        }
    } else {
        // ---------- reducer: waits on workers (never the other way) ----------
        if (t >= 64) return;
        for (int i = t; i < TOTAL_BLOCKS; i += 64) {
            while (__hip_atomic_load(&flags[i], __ATOMIC_ACQUIRE,
                                     __HIP_MEMORY_SCOPE_AGENT) != 1u)
                __builtin_amdgcn_s_sleep(2);
        }
        __threadfence();
        float ssum = 0.f;
        for (int i = t; i < NPART; i += 64)
            ssum += __hip_atomic_load(&part[i], __ATOMIC_RELAXED,
                                      __HIP_MEMORY_SCOPE_AGENT);
        for (int off = 32; off >= 1; off >>= 1) ssum += __shfl_down(ssum, off);
        if (t == 0) out[0] = ssum;
        // self-reset so next replay is correct even if ws poisoning is skipped
        for (int i = t; i < TOTAL_BLOCKS; i += 64)
            __hip_atomic_store(&flags[i], 0u, __ATOMIC_RELAXED,
                               __HIP_MEMORY_SCOPE_AGENT);
    }
}

extern "C" void kernel_launch(void* const* d_in, const int* in_sizes, int n_in,
                              void* d_out, int out_size, void* d_ws, size_t ws_size,
                              hipStream_t stream)
{
    const float* pcl    = (const float*)d_in[0];
    const float* trans  = (const float*)d_in[1];
    const float* rot    = (const float*)d_in[2];
    const float* sizep  = (const float*)d_in[3];
    const float* seps   = (const float*)d_in[4];
    const float* deform = (const float*)d_in[5];
    const float* probs  = (const float*)d_in[6];
    const float* etas   = (const float*)d_in[7];
    const float* omegas = (const float*)d_in[8];
    float* out = (float*)d_out;
    float* partials = (float*)d_ws;                       // [0, 5120) bytes
    unsigned int* flags = (unsigned int*)((char*)d_ws + 8192);  // [8192, 10240)

    k_all<<<TOTAL_BLOCKS + 1, 256, 0, stream>>>(pcl, trans, rot, sizep, seps,
                                                deform, probs, etas, omegas,
                                                partials, flags, out);
}

// Round 5
// 90.264 us; speedup vs baseline: 1.1517x; 1.0163x over previous
//
#include <hip/hip_runtime.h>
#include <math.h>

#define EPSF 1e-6f

constexpr int B = 8, N = 2048, M = 16, S = 100;
constexpr int MAIN_BLOCKS = B * (N / 64);         // 256: pcl_to_prim, 64 points each
constexpr int PRIM_BLOCKS = B * M * 2;            // 256: prim_to_pcl, (b,m) x half-of-S
constexpr int TOTAL_BLOCKS = MAIN_BLOCKS + PRIM_BLOCKS;  // 512 worker blocks
constexpr int NPART = MAIN_BLOCKS * 4 + PRIM_BLOCKS;     // 1280 partials in d_ws

typedef float v2f __attribute__((ext_vector_type(2)));   // -> v_pk_fma_f32 pairs

// fast hw transcendentals (avoid __exp2f/__log2f: glibc math.h macro collision)
__device__ __forceinline__ float hw_exp2(float x) { return __builtin_amdgcn_exp2f(x); }
__device__ __forceinline__ float hw_log2(float x) { return __builtin_amdgcn_logf(x); }

__device__ __forceinline__ float fexp_d(float x, float p) {
    float sg = (x > 0.f) ? 1.f : ((x < 0.f) ? -1.f : 0.f);
    return sg * __powf(fabsf(x) + EPSF, p);
}

__device__ __forceinline__ float sgn_d(float x) {
    return (x > 0.f) ? 1.f : ((x < 0.f) ? -1.f : 0.f);
}

// quaternion (w,x,y,z) at rot[bm*4..] -> row-major 3x3
__device__ __forceinline__ void quat_R(const float* __restrict__ rot, int bm, float R[9]) {
    float w = rot[bm * 4 + 0], x = rot[bm * 4 + 1], y = rot[bm * 4 + 2], z = rot[bm * 4 + 3];
    float inv = 1.0f / (sqrtf(w * w + x * x + y * y + z * z) + EPSF);
    w *= inv; x *= inv; y *= inv; z *= inv;
    R[0] = 1.f - 2.f * (y * y + z * z); R[1] = 2.f * (x * y - w * z); R[2] = 2.f * (x * z + w * y);
    R[3] = 2.f * (x * y + w * z); R[4] = 1.f - 2.f * (x * x + z * z); R[5] = 2.f * (y * z - w * x);
    R[6] = 2.f * (x * z - w * y); R[7] = 2.f * (y * z + w * x); R[8] = 1.f - 2.f * (x * x + y * y);
}

// surface point (prim path; 50 pts/block, transcendental cost irrelevant there)
__device__ __forceinline__ float4 surf_point(
    const float* __restrict__ sizep, const float* __restrict__ seps,
    const float* __restrict__ deform, const float* __restrict__ etas,
    const float* __restrict__ omegas, int bm, int s)
{
    float e1 = seps[bm * 2 + 0], e2 = seps[bm * 2 + 1];
    float a1 = sizep[bm * 3 + 0], a2 = sizep[bm * 3 + 1], a3 = sizep[bm * 3 + 2];
    float d0 = deform[bm * 2 + 0], d1 = deform[bm * 2 + 1];
    float se_, ce_, sw_, cw_;
    __sincosf(etas[s], &se_, &ce_);
    __sincosf(omegas[s], &sw_, &cw_);
    float ce = fexp_d(ce_, e1);
    float se = fexp_d(se_, e1);
    float cw = fexp_d(cw_, e2);
    float sw = fexp_d(sw_, e2);
    float x = a1 * ce * cw;
    float y = a2 * ce * sw;
    float z = a3 * se;
    float fx = d0 * (z / a3) + 1.0f;
    float fy = d1 * (z / a3) + 1.0f;
    float4 P;
    P.x = fx * x; P.y = fy * y; P.z = z;
    P.w = P.x * P.x + P.y * P.y + P.z * P.z;
    return P;
}

// ---------------- single fused kernel, 513 blocks ----------------
// [0,256): pcl_to_prim; [256,512): prim_to_pcl; block 512: flag-gated reducer.
// No same-address atomics anywhere (round-1 lesson: ~14 ns each, serialized).
// Flags are agent-scope release/acquire and self-resetting, so correctness
// depends neither on dispatch order (workers never wait) nor on ws poisoning.
__global__ __launch_bounds__(256) void k_all(
    const float* __restrict__ pcl, const float* __restrict__ trans,
    const float* __restrict__ rot, const float* __restrict__ sizep,
    const float* __restrict__ seps, const float* __restrict__ deform,
    const float* __restrict__ probs,
    const float* __restrict__ etas, const float* __restrict__ omegas,
    float* __restrict__ part, unsigned int* __restrict__ flags,
    float* __restrict__ out)
{
    __shared__ float4 pts[S * M];   // 25.6 KB  (prim path reuses [0..49])
    __shared__ float trig[S * 8];   // 3.2 KB: per-s {log2|c|,sgn} x {ce,se,cw,sw}
    __shared__ float sbuf[20];      // prim path: sarea[0..15], wsum[16..19]

    int t = threadIdx.x;

    if (blockIdx.x < MAIN_BLOCKS) {
        // ---------- pcl_to_prim ----------
        int b  = blockIdx.x >> 5;        // 32 n-chunks per batch
        int n0 = (blockIdx.x & 31) * 64;

        // stage 1: per-s trig+log table (sincos/log depend only on s, not m)
        if (t < S) {
            float se_, ce_, sw_, cw_;
            __sincosf(etas[t], &se_, &ce_);
            __sincosf(omegas[t], &sw_, &cw_);
            trig[t * 8 + 0] = hw_log2(fabsf(ce_) + EPSF);
            trig[t * 8 + 1] = sgn_d(ce_);
            trig[t * 8 + 2] = hw_log2(fabsf(se_) + EPSF);
            trig[t * 8 + 3] = sgn_d(se_);
            trig[t * 8 + 4] = hw_log2(fabsf(cw_) + EPSF);
            trig[t * 8 + 5] = sgn_d(cw_);
            trig[t * 8 + 6] = hw_log2(fabsf(sw_) + EPSF);
            trig[t * 8 + 7] = sgn_d(sw_);
        }
        __syncthreads();

        // stage 2: 1600 surface points, 4 exp2 each (was 12 transcendentals)
        for (int i = t; i < S * M; i += 256) {
            int s = i >> 4, mm = i & 15;
            int bmi = b * M + mm;
            float e1 = seps[bmi * 2 + 0], e2 = seps[bmi * 2 + 1];
            float a1 = sizep[bmi * 3 + 0], a2 = sizep[bmi * 3 + 1], a3 = sizep[bmi * 3 + 2];
            float d0 = deform[bmi * 2 + 0], d1 = deform[bmi * 2 + 1];
            float ce = trig[s * 8 + 1] * hw_exp2(e1 * trig[s * 8 + 0]);
            float se = trig[s * 8 + 3] * hw_exp2(e1 * trig[s * 8 + 2]);
            float cw = trig[s * 8 + 5] * hw_exp2(e2 * trig[s * 8 + 4]);
            float sw = trig[s * 8 + 7] * hw_exp2(e2 * trig[s * 8 + 6]);
            float x = a1 * ce * cw;
            float y = a2 * ce * sw;
            float z = a3 * se;
            float fx = fmaf(d0, se, 1.0f);   // z/a3 == se
            float fy = fmaf(d1, se, 1.0f);
            float4 P;
            P.x = fx * x; P.y = fy * y; P.z = z;
            P.w = P.x * P.x + P.y * P.y + P.z * P.z;
            pts[i] = P;
        }
        __syncthreads();

        int m  = t & 15;
        int nl = t >> 4;
        int bm = b * M + m;
        float R[9];
        quat_R(rot, bm, R);
        float tx = trans[bm * 3 + 0], ty = trans[bm * 3 + 1], tz = trans[bm * 3 + 2];

        // rotated points; j packed in pairs for v_pk_fma_f32
        v2f mx2[2], my2[2], mz2[2], dmin2[2];
        float psq[4];
#pragma unroll
        for (int j = 0; j < 4; j++) {
            int n = n0 + nl + 16 * j;
            float px = pcl[(b * N + n) * 3 + 0];
            float py = pcl[(b * N + n) * 3 + 1];
            float pz = pcl[(b * N + n) * 3 + 2];
            float dx = px - tx, dy = py - ty, dz = pz - tz;
            float X = R[0] * dx + R[1] * dy + R[2] * dz;
            float Y = R[3] * dx + R[4] * dy + R[5] * dz;
            float Z = R[6] * dx + R[7] * dy + R[8] * dz;
            mx2[j >> 1][j & 1] = -2.f * X;
            my2[j >> 1][j & 1] = -2.f * Y;
            mz2[j >> 1][j & 1] = -2.f * Z;
            psq[j] = X * X + Y * Y + Z * Z;
            dmin2[j >> 1][j & 1] = 3.4e38f;
        }

        // min over s of (|P|^2 - 2 P.pt); ping-pong buffers, manual 2x unroll
        // (kills the 16-v_mov buffer copy of the old rotate; packed fma bodies)
        auto compute4 = [&](const float4* P4) {
#pragma unroll
            for (int u = 0; u < 4; u++) {
                float4 P = P4[u];
                v2f vx = {P.x, P.x}, vy = {P.y, P.y}, vz = {P.z, P.z}, vw = {P.w, P.w};
#pragma unroll
                for (int p = 0; p < 2; p++) {
                    v2f d = __builtin_elementwise_fma(vx, mx2[p], vw);
                    d = __builtin_elementwise_fma(vy, my2[p], d);
                    d = __builtin_elementwise_fma(vz, mz2[p], d);
                    dmin2[p] = __builtin_elementwise_min(dmin2[p], d);
                }
            }
        };

        float4 Pa[4], Pb[4];
#pragma unroll
        for (int u = 0; u < 4; u++) Pa[u] = pts[u * M + m];
        for (int g = 0; g < 24; g += 2) {           // groups of 4 s; 25 groups total
#pragma unroll
            for (int u = 0; u < 4; u++) Pb[u] = pts[(4 * (g + 1) + u) * M + m];
            compute4(Pa);
#pragma unroll
            for (int u = 0; u < 4; u++) Pa[u] = pts[(4 * (g + 2) + u) * M + m];
            compute4(Pb);
        }
        compute4(Pa);                               // group 24 (s=96..99)

        // ---- in-wave cumprod-sorted sum ----
        float ompr[16];
#pragma unroll
        for (int k = 0; k < 16; k++) ompr[k] = 1.f - probs[b * M + k];
        float pv  = probs[bm];
        float acc = 0.f;
#pragma unroll
        for (int j = 0; j < 4; j++) {
            float key = dmin2[j >> 1][j & 1] + psq[j];
            float prod = 1.f;
#pragma unroll
            for (int k = 0; k < 16; k++) {
                float bk = __shfl(key, k, 16);
                bool before = (bk < key) || (bk == key && k < m);
                prod *= before ? ompr[k] : 1.f;
            }
            acc += key * pv * prod;
        }
        for (int off = 32; off >= 1; off >>= 1) acc += __shfl_down(acc, off);
        if ((t & 63) == 0)
            __hip_atomic_store(&part[blockIdx.x * 4 + (t >> 6)],
                               acc * (1.0f / (B * N)),
                               __ATOMIC_RELAXED, __HIP_MEMORY_SCOPE_AGENT);
        __syncthreads();   // all four partial stores issued before flag
        if (t == 0)
            __hip_atomic_store(&flags[blockIdx.x], 1u,
                               __ATOMIC_RELEASE, __HIP_MEMORY_SCOPE_AGENT);
    } else if (blockIdx.x < TOTAL_BLOCKS) {
        // ---------- prim_to_pcl ----------
        int pb = blockIdx.x - MAIN_BLOCKS;
        int bm = pb >> 1, q = pb & 1;
        int b = bm >> 4, m = bm & 15;
        int s0 = q * 50;

        float4* spts = pts;          // [0..49]
        float* sarea = sbuf;         // [0..15]
        float* wsum  = sbuf + 16;    // [16..19]

        if (t < 50) spts[t] = surf_point(sizep, seps, deform, etas, omegas, bm, s0 + t);
        if (t >= 64 && t < 64 + M) {
            int mm = t - 64;
            float s0s = sizep[(b * M + mm) * 3 + 0];
            float s1s = sizep[(b * M + mm) * 3 + 1];
            float s2s = sizep[(b * M + mm) * 3 + 2];
            float tt = __powf(s0s * s1s, 1.6f) / 3.f + __powf(s0s * s2s, 1.6f) / 3.f
                     + __powf(s1s * s2s, 1.6f) / 3.f;
            sarea[mm] = 4.0f * 3.14159265358979323846f * __powf(tt, 0.625f);
        }
        __syncthreads();

        float R[9];
        quat_R(rot, bm, R);
        float tx = trans[bm * 3 + 0], ty = trans[bm * 3 + 1], tz = trans[bm * 3 + 2];

        int w = t >> 6, lane = t & 63;
        int cnt = (w < 2) ? 13 : 12;
        int off = (w < 2) ? w * 13 : 26 + (w - 2) * 12;

        // 14 slots packed into 7 v2f pairs (pads map to slot 'off', masked later)
        v2f px2[7], py2[7], pz2[7], mins2[7];
#pragma unroll
        for (int k = 0; k < 14; k++) {
            int sl = (k < cnt) ? (off + k) : off;
            float4 P = spts[sl];
            px2[k >> 1][k & 1] = P.x;
            py2[k >> 1][k & 1] = P.y;
            pz2[k >> 1][k & 1] = P.z;
            mins2[k >> 1][k & 1] = 3.4e38f;
        }

        // min over n; 1-deep global prefetch hides L2 latency; packed fma body
        const float* pcb = pcl + b * N * 3;
        float cx = pcb[lane * 3 + 0], cy = pcb[lane * 3 + 1], cz = pcb[lane * 3 + 2];
        for (int i = 0; i < 32; i++) {
            int n2 = (i < 31) ? ((i + 1) * 64 + lane) : lane;
            float nx = pcb[n2 * 3 + 0], ny = pcb[n2 * 3 + 1], nz = pcb[n2 * 3 + 2];
            float dx = cx - tx, dy = cy - ty, dz = cz - tz;
            float X = R[0] * dx + R[1] * dy + R[2] * dz;
            float Y = R[3] * dx + R[4] * dy + R[5] * dz;
            float Z = R[6] * dx + R[7] * dy + R[8] * dz;
            float Xsq = X * X + Y * Y + Z * Z;
            v2f vmX = {-2.f * X, -2.f * X}, vmY = {-2.f * Y, -2.f * Y};
            v2f vmZ = {-2.f * Z, -2.f * Z}, vXq = {Xsq, Xsq};
#pragma unroll
            for (int k = 0; k < 7; k++) {
                v2f d = __builtin_elementwise_fma(px2[k], vmX, vXq);
                d = __builtin_elementwise_fma(py2[k], vmY, d);
                d = __builtin_elementwise_fma(pz2[k], vmZ, d);
                mins2[k] = __builtin_elementwise_min(mins2[k], d);
            }
            cx = nx; cy = ny; cz = nz;
        }

        float sum = 0.f;
#pragma unroll
        for (int k = 0; k < 14; k++) {
            float v = mins2[k >> 1][k & 1];
            for (int o = 32; o >= 1; o >>= 1) v = fminf(v, __shfl_down(v, o));
            int sl = (k < cnt) ? (off + k) : off;
            v += spts[sl].w;
            sum += (k < cnt) ? v : 0.f;
        }

        if (lane == 0) wsum[w] = sum;
        __syncthreads();
        if (t == 0) {
            float total = wsum[0] + wsum[1] + wsum[2] + wsum[3];
            float asum = 0.f;
            for (int mm = 0; mm < M; mm++) asum += sarea[mm];
            float area = (float)M * sarea[m] / asum;
            __hip_atomic_store(&part[MAIN_BLOCKS * 4 + pb],
                               total * area * (1.0f / (S * B * M)),
                               __ATOMIC_RELAXED, __HIP_MEMORY_SCOPE_AGENT);
            __hip_atomic_store(&flags[blockIdx.x], 1u,
                               __ATOMIC_RELEASE, __HIP_MEMORY_SCOPE_AGENT);
        }
    } else {
        // ---------- reducer: waits on workers (never the other way) ----------
        if (t >= 64) return;
        for (int i = t; i < TOTAL_BLOCKS; i += 64) {
            while (__hip_atomic_load(&flags[i], __ATOMIC_ACQUIRE,
                                     __HIP_MEMORY_SCOPE_AGENT) != 1u)
                __builtin_amdgcn_s_sleep(2);
        }
        __threadfence();
        float ssum = 0.f;
        for (int i = t; i < NPART; i += 64)
            ssum += __hip_atomic_load(&part[i], __ATOMIC_RELAXED,
                                      __HIP_MEMORY_SCOPE_AGENT);
        for (int off = 32; off >= 1; off >>= 1) ssum += __shfl_down(ssum, off);
        if (t == 0) out[0] = ssum;
        // self-reset so next replay is correct even if ws poisoning is skipped
        for (int i = t; i < TOTAL_BLOCKS; i += 64)
            __hip_atomic_store(&flags[i], 0u, __ATOMIC_RELAXED,
                               __HIP_MEMORY_SCOPE_AGENT);
    }
}

extern "C" void kernel_launch(void* const* d_in, const int* in_sizes, int n_in,
                              void* d_out, int out_size, void* d_ws, size_t ws_size,
                              hipStream_t stream)
{
    const float* pcl    = (const float*)d_in[0];
    const float* trans  = (const float*)d_in[1];
    const float* rot    = (const float*)d_in[2];
    const float* sizep  = (const float*)d_in[3];
    const float* seps   = (const float*)d_in[4];
    const float* deform = (const float*)d_in[5];
    const float* probs  = (const float*)d_in[6];
    const float* etas   = (const float*)d_in[7];
    const float* omegas = (const float*)d_in[8];
    float* out = (float*)d_out;
    float* partials = (float*)d_ws;                       // [0, 5120) bytes
    unsigned int* flags = (unsigned int*)((char*)d_ws + 8192);  // [8192, 10240)

    k_all<<<TOTAL_BLOCKS + 1, 256, 0, stream>>>(pcl, trans, rot, sizep, seps,
                                                deform, probs, etas, omegas,
                                                partials, flags, out);
}